// Round 11
// baseline (120.169 us; speedup 1.0000x reference)
//
#include <hip/hip_runtime.h>
#include <hip/hip_bf16.h>
#include <stdint.h>

#define ALPHA 0.2f

typedef __attribute__((ext_vector_type(8))) short bf16x8;
typedef __attribute__((ext_vector_type(4))) float f32x4;

__device__ __forceinline__ short f2bf(float f) {
    union { float f; uint32_t u; } c; c.f = f;
    uint32_t u = c.u + 0x7FFF + ((c.u >> 16) & 1);   // round-to-nearest-even
    return (short)(u >> 16);
}

// pack two fp32 -> packed bf16 pair (round-half-up)
__device__ __forceinline__ uint32_t pk_bf16(float lo, float hi) {
    union { float f; uint32_t u; } a, b;
    a.f = lo; b.f = hi;
    return __builtin_amdgcn_perm(b.u + 0x8000u, a.u + 0x8000u, 0x07060302u);
}

// async global->LDS, 16 B per lane. l must be wave-uniform; g is per-lane.
__device__ __forceinline__ void gload_lds16(const void* g, void* l) {
    __builtin_amdgcn_global_load_lds(
        (const __attribute__((address_space(1))) void*)g,
        (__attribute__((address_space(3))) void*)l, 16, 0, 0);
}

// ---------------------------------------------------------------------------
// Kernel 0: pack adj into byte-masks (8 ints -> 1 byte per thread). First 64
// blocks also pre-transpose W (fp32 [k][f]) -> WTg (bf16 [f][k]).
// ---------------------------------------------------------------------------
__global__ __launch_bounds__(256) void pack_adj_kernel(
        const int* __restrict__ adj, uint8_t* __restrict__ bytes,
        const float* __restrict__ W, short* __restrict__ WTg) {
    int t = blockIdx.x * 256 + threadIdx.x;            // 524288 threads
    const int4* a4 = reinterpret_cast<const int4*>(adj) + (size_t)t * 2;
    int4 x0 = a4[0], x1 = a4[1];
    uint32_t m = 0;
    m |= (x0.x > 0) ? 1u   : 0u;  m |= (x0.y > 0) ? 2u   : 0u;
    m |= (x0.z > 0) ? 4u   : 0u;  m |= (x0.w > 0) ? 8u   : 0u;
    m |= (x1.x > 0) ? 16u  : 0u;  m |= (x1.y > 0) ? 32u  : 0u;
    m |= (x1.z > 0) ? 64u  : 0u;  m |= (x1.w > 0) ? 128u : 0u;
    bytes[t] = (uint8_t)m;

    if (blockIdx.x < 64) {
        int idx = blockIdx.x * 256 + threadIdx.x;
        int k = idx >> 7, f = idx & 127;
        WTg[f * 128 + k] = f2bf(W[k * 128 + f]);
    }
}

// ---------------------------------------------------------------------------
// Kernel 1: Wh = h @ W; epilogue: s1/s2 and whT in MFMA-frag-ordered chunk
// layout: chunk (b,jc) is 8 KB; element (f, jo) at
//   chunkbase + t*512 + qg*128 + n*8 + jj   (shorts)
// XCD swizzle: b = blockIdx & 7. Grid 1024 x 256 thr.
// ---------------------------------------------------------------------------
__global__ __launch_bounds__(256) void wh_kernel(
        const float* __restrict__ h, const short* __restrict__ WTg,
        const float* __restrict__ a, short* __restrict__ whT,
        float* __restrict__ s1g, float* __restrict__ s2g) {
    __shared__ float sred[4][2][16];
    __shared__ short tr[4][32][24];

    int tid = threadIdx.x, wid = tid >> 6, lane = tid & 63;
    int q = lane >> 4, n = lane & 15;
    int bb = blockIdx.x & 7;                           // XCD-local batch
    int tile = blockIdx.x >> 3;                        // 0..127
    int rb = bb * 2048 + tile * 16;                    // global row base
    int row = rb + n;

    f32x4 acc[2] = {};
    #pragma unroll
    for (int kc = 0; kc < 4; ++kc) {
        const float* hp = h + (size_t)row * 128 + kc * 32 + q * 8;
        float4 h0 = reinterpret_cast<const float4*>(hp)[0];
        float4 h1 = reinterpret_cast<const float4*>(hp)[1];
        bf16x8 afrag;
        afrag[0] = f2bf(h0.x); afrag[1] = f2bf(h0.y);
        afrag[2] = f2bf(h0.z); afrag[3] = f2bf(h0.w);
        afrag[4] = f2bf(h1.x); afrag[5] = f2bf(h1.y);
        afrag[6] = f2bf(h1.z); afrag[7] = f2bf(h1.w);
        #pragma unroll
        for (int u = 0; u < 2; ++u) {
            int t = wid * 2 + u;
            bf16x8 bfrag = *reinterpret_cast<const bf16x8*>(
                WTg + (t * 16 + n) * 128 + kc * 32 + q * 8);
            acc[u] = __builtin_amdgcn_mfma_f32_16x16x32_bf16(afrag, bfrag, acc[u], 0, 0, 0);
        }
    }

    float p1[4] = {0.f, 0.f, 0.f, 0.f}, p2[4] = {0.f, 0.f, 0.f, 0.f};
    #pragma unroll
    for (int u = 0; u < 2; ++u) {
        int c = (wid * 2 + u) * 16 + n;
        float a1c = a[c], a2c = a[128 + c];
        #pragma unroll
        for (int r = 0; r < 4; ++r) {
            p1[r] += acc[u][r] * a1c;
            p2[r] += acc[u][r] * a2c;
        }
    }
    #pragma unroll
    for (int d = 1; d < 16; d <<= 1) {
        #pragma unroll
        for (int r = 0; r < 4; ++r) {
            p1[r] += __shfl_xor(p1[r], d);
            p2[r] += __shfl_xor(p2[r], d);
        }
    }
    if (n == 0) {
        #pragma unroll
        for (int r = 0; r < 4; ++r) {
            sred[wid][0][q * 4 + r] = p1[r];
            sred[wid][1][q * 4 + r] = p2[r];
        }
    }

    #pragma unroll
    for (int u = 0; u < 2; ++u)
        #pragma unroll
        for (int r = 0; r < 4; ++r)
            tr[wid][u * 16 + n][q * 4 + r] = f2bf(acc[u][r]);
    __syncthreads();

    if (wid == 0 && lane < 16) {
        float v1 = 0.f, v2 = 0.f;
        #pragma unroll
        for (int v = 0; v < 4; ++v) { v1 += sred[v][0][lane]; v2 += sred[v][1][lane]; }
        s1g[rb + lane] = v1;
        s2g[rb + lane] = v2;
    }

    int jr = rb & 2047;
    int fl = lane & 31, jh = lane >> 5;
    bf16x8 v = *reinterpret_cast<const bf16x8*>(&tr[wid][fl][jh * 8]);
    int f = wid * 32 + fl;
    int t = f >> 4, nn = f & 15;
    int jc = jr >> 5;
    int qg = ((jr & 31) >> 3) + jh;                    // jo>>3 for this 8-run
    *reinterpret_cast<bf16x8*>(
        whT + (size_t)(bb * 64 + jc) * 4096 + t * 512 + qg * 128 + nn * 8) = v;
}

// ---------------------------------------------------------------------------
// Kernel 2 (v11): fused masked-softmax attention + PV, AITER-style pipelined
// K-loop: 4-slot 8 KB LDS ring, staging 3 steps ahead, raw s_barrier with
// s_waitcnt vmcnt(4) (NEVER vmcnt(0) — the v10 __syncthreads drain was the
// ~2k-cy/step serializer). Masks (pitch-65 LDS) and s2 staged to LDS once;
// the K-loop's only VMEM is the 2 staging loads/wave/step.
// Grid 256 (8 XCD-aligned b x 32 i-tiles of 64 rows) x 256 thr; wave w owns
// rows ib+w*16..+16 over full j (no combine).
// ---------------------------------------------------------------------------
__global__ __launch_bounds__(256) void attn_kernel(
        const short* __restrict__ whT, const float* __restrict__ s1g,
        const float* __restrict__ s2g, const uint8_t* __restrict__ adjb,
        float* __restrict__ out) {
    __shared__ char sbuf[4][8192];                     // 32 KB B ring
    __shared__ uint32_t mlds[64 * 65];                 // 16.6 KB masks, pitch 65
    __shared__ float s2lds[2048];                      // 8 KB s2

    int tid = threadIdx.x, wid = tid >> 6, lane = tid & 63;
    int q = lane >> 4, n = lane & 15;
    int b  = blockIdx.x & 7;                           // XCD-local batch
    int ib = (blockIdx.x >> 3) * 64;                   // i-tile base
    int rowA = ib + wid * 16 + n;                      // this wave's row (m=n)

    float s1A = s1g[b * 2048 + rowA];
    const float* s2b = s2g + b * 2048;
    const char* gbase = reinterpret_cast<const char*>(whT) + (size_t)b * 524288;

    // ---- stage masks: row rt (64 rows of this i-tile), pitch 65 dwords
    {
        int rt = tid >> 2, seg = tid & 3;
        const uint4* src = reinterpret_cast<const uint4*>(
            adjb + (size_t)(ib + rt) * 256 + seg * 64);
        uint32_t* dst = &mlds[rt * 65 + seg * 16];
        #pragma unroll
        for (int i = 0; i < 4; ++i) {
            uint4 v = src[i];
            dst[i * 4 + 0] = v.x; dst[i * 4 + 1] = v.y;
            dst[i * 4 + 2] = v.z; dst[i * 4 + 3] = v.w;
        }
    }
    // ---- stage s2 (2048 floats)
    {
        float4 v0 = *reinterpret_cast<const float4*>(s2b + tid * 8);
        float4 v1 = *reinterpret_cast<const float4*>(s2b + tid * 8 + 4);
        *reinterpret_cast<float4*>(&s2lds[tid * 8])     = v0;
        *reinterpret_cast<float4*>(&s2lds[tid * 8 + 4]) = v1;
    }

    // ---- prologue: stage chunks 0..2 into ring slots 0..2 (2 loads/wave ea)
    #pragma unroll
    for (int s0 = 0; s0 < 3; ++s0) {
        const char* g = gbase + s0 * 8192 + wid * 2048 + lane * 16;
        char* l = &sbuf[s0][wid * 2048];
        gload_lds16(g, l);
        gload_lds16(g + 1024, l + 1024);
    }
    asm volatile("s_waitcnt vmcnt(4) lgkmcnt(0)" ::: "memory");
    asm volatile("s_barrier" ::: "memory");

    f32x4 acc[8] = {};
    float ds = 0.f;
    int mbase = (wid * 16 + n) * 65;

    for (int s = 0; s < 64; ++s) {
        // ---- issue staging for chunk s+3 (clamped at tail: writes land in a
        // dead slot whose last reader already finished — keeps vmcnt uniform)
        int sn = (s + 3 <= 63) ? s + 3 : 63;
        {
            const char* g = gbase + (size_t)sn * 8192 + wid * 2048 + lane * 16;
            char* l = &sbuf[(s + 3) & 3][wid * 2048];
            gload_lds16(g, l);
            gload_lds16(g + 1024, l + 1024);
        }

        // ---- B frags for chunk s from ring (lane*16 contiguous, no conflict)
        const char* cb = &sbuf[s & 3][0] + lane * 16;
        bf16x8 nb[8];
        #pragma unroll
        for (int t = 0; t < 8; ++t)
            nb[t] = *reinterpret_cast<const bf16x8*>(cb + t * 1024);

        // ---- mask dword + s2 from LDS (broadcast/conflict-free)
        uint32_t mA = mlds[mbase + s] >> (q * 8);
        float4 s2a = *reinterpret_cast<const float4*>(&s2lds[s * 32 + q * 8]);
        float4 s2c = *reinterpret_cast<const float4*>(&s2lds[s * 32 + q * 8 + 4]);
        float s2arr[8] = {s2a.x, s2a.y, s2a.z, s2a.w,
                          s2c.x, s2c.y, s2c.z, s2c.w};

        // ---- P for chunk s
        float p[8];
        #pragma unroll
        for (int j = 0; j < 8; ++j) {
            float e = s1A + s2arr[j];
            e = fmaxf(e, ALPHA * e);
            float v = ((mA >> j) & 1) ? __expf(e) : 0.0f;
            ds += v; p[j] = v;
        }
        union { uint32_t u32[4]; bf16x8 v; } cv;
        #pragma unroll
        for (int pp = 0; pp < 4; ++pp)
            cv.u32[pp] = pk_bf16(p[2 * pp], p[2 * pp + 1]);

        #pragma unroll
        for (int t = 0; t < 8; ++t)
            acc[t] = __builtin_amdgcn_mfma_f32_16x16x32_bf16(cv.v, nb[t], acc[t], 0, 0, 0);

        // ---- fine-grained sync: wait only until chunk s+1's staging is home
        // (4 newer loads stay in flight), then raw barrier (NO vmcnt(0) drain)
        asm volatile("s_waitcnt vmcnt(4)" ::: "memory");
        asm volatile("s_barrier" ::: "memory");
    }

    // ---- denominators (row m in lanes m, m+16, m+32, m+48) — wave-private
    ds += __shfl_xor(ds, 16); ds += __shfl_xor(ds, 32);
    float rd[4];
    #pragma unroll
    for (int r = 0; r < 4; ++r) rd[r] = 1.0f / __shfl(ds, q * 4 + r);

    size_t ob = ((size_t)b * 2048 + ib + wid * 16) * 128;
    #pragma unroll
    for (int t = 0; t < 8; ++t)
        #pragma unroll
        for (int r = 0; r < 4; ++r)
            out[ob + (size_t)(q * 4 + r) * 128 + t * 16 + n] = acc[t][r] * rd[r];
}

// ---------------------------------------------------------------------------
extern "C" void kernel_launch(void* const* d_in, const int* in_sizes, int n_in,
                              void* d_out, int out_size, void* d_ws, size_t ws_size,
                              hipStream_t stream) {
    const float* h   = (const float*)d_in[0];   // [8][2048][128] f32
    const int*   adj = (const int*)d_in[1];     // [2048][2048] i32
    const float* W   = (const float*)d_in[2];   // [128][128] f32
    const float* a   = (const float*)d_in[3];   // [256][1] f32
    float* out = (float*)d_out;                 // [8][2048][128] f32

    char* ws = (char*)d_ws;
    short* whT = (short*)ws;                                  // 4 MB  bf16 whT (chunk-tiled)
    float* s1  = (float*)(ws + 4194304);                      // 64 KB
    float* s2  = (float*)(ws + 4259840);                      // 64 KB
    uint8_t* bytes = (uint8_t*)(ws + 4325376);                // 512 KB

    // WT scratch in the tail of d_out (32 KB); wh reads it before attn
    // overwrites d_out. Same-stream ordering makes this safe.
    short* WTg = (short*)d_out + (4194304 - 16384);

    pack_adj_kernel<<<2048, 256, 0, stream>>>(adj, bytes, W, WTg);
    wh_kernel<<<1024, 256, 0, stream>>>(h, WTg, a, whT, s1, s2);
    attn_kernel<<<256, 256, 0, stream>>>(whT, s1, s2, bytes, out);
}

// Round 12
// 108.176 us; speedup vs baseline: 1.1109x; 1.1109x over previous
//
#include <hip/hip_runtime.h>
#include <hip/hip_bf16.h>
#include <stdint.h>

#define ALPHA 0.2f

typedef __attribute__((ext_vector_type(8))) short bf16x8;
typedef __attribute__((ext_vector_type(4))) float f32x4;

__device__ __forceinline__ short f2bf(float f) {
    union { float f; uint32_t u; } c; c.f = f;
    uint32_t u = c.u + 0x7FFF + ((c.u >> 16) & 1);   // round-to-nearest-even
    return (short)(u >> 16);
}

// pack two fp32 -> packed bf16 pair (round-half-up)
__device__ __forceinline__ uint32_t pk_bf16(float lo, float hi) {
    union { float f; uint32_t u; } a, b;
    a.f = lo; b.f = hi;
    return __builtin_amdgcn_perm(b.u + 0x8000u, a.u + 0x8000u, 0x07060302u);
}

// async global->LDS, 16 B per lane. l must be wave-uniform; g is per-lane.
__device__ __forceinline__ void gload_lds16(const void* g, void* l) {
    __builtin_amdgcn_global_load_lds(
        (const __attribute__((address_space(1))) void*)g,
        (__attribute__((address_space(3))) void*)l, 16, 0, 0);
}

// ---------------------------------------------------------------------------
// Kernel 0: pack adj into byte-masks (8 ints -> 1 byte per thread). First 64
// blocks also pre-transpose W (fp32 [k][f]) -> WTg (bf16 [f][k]).
// ---------------------------------------------------------------------------
__global__ __launch_bounds__(256) void pack_adj_kernel(
        const int* __restrict__ adj, uint8_t* __restrict__ bytes,
        const float* __restrict__ W, short* __restrict__ WTg) {
    int t = blockIdx.x * 256 + threadIdx.x;            // 524288 threads
    const int4* a4 = reinterpret_cast<const int4*>(adj) + (size_t)t * 2;
    int4 x0 = a4[0], x1 = a4[1];
    uint32_t m = 0;
    m |= (x0.x > 0) ? 1u   : 0u;  m |= (x0.y > 0) ? 2u   : 0u;
    m |= (x0.z > 0) ? 4u   : 0u;  m |= (x0.w > 0) ? 8u   : 0u;
    m |= (x1.x > 0) ? 16u  : 0u;  m |= (x1.y > 0) ? 32u  : 0u;
    m |= (x1.z > 0) ? 64u  : 0u;  m |= (x1.w > 0) ? 128u : 0u;
    bytes[t] = (uint8_t)m;

    if (blockIdx.x < 64) {
        int idx = blockIdx.x * 256 + threadIdx.x;
        int k = idx >> 7, f = idx & 127;
        WTg[f * 128 + k] = f2bf(W[k * 128 + f]);
    }
}

// ---------------------------------------------------------------------------
// Kernel 1: Wh = h @ W; epilogue: s1/s2 and whT in MFMA-frag-ordered chunk
// layout: chunk (b,jc) is 8 KB; element (f, jo) at
//   chunkbase + t*512 + qg*128 + n*8 + jj   (shorts)
// XCD swizzle: b = blockIdx & 7. Grid 1024 x 256 thr.
// ---------------------------------------------------------------------------
__global__ __launch_bounds__(256) void wh_kernel(
        const float* __restrict__ h, const short* __restrict__ WTg,
        const float* __restrict__ a, short* __restrict__ whT,
        float* __restrict__ s1g, float* __restrict__ s2g) {
    __shared__ float sred[4][2][16];
    __shared__ short tr[4][32][24];

    int tid = threadIdx.x, wid = tid >> 6, lane = tid & 63;
    int q = lane >> 4, n = lane & 15;
    int bb = blockIdx.x & 7;                           // XCD-local batch
    int tile = blockIdx.x >> 3;                        // 0..127
    int rb = bb * 2048 + tile * 16;                    // global row base
    int row = rb + n;

    f32x4 acc[2] = {};
    #pragma unroll
    for (int kc = 0; kc < 4; ++kc) {
        const float* hp = h + (size_t)row * 128 + kc * 32 + q * 8;
        float4 h0 = reinterpret_cast<const float4*>(hp)[0];
        float4 h1 = reinterpret_cast<const float4*>(hp)[1];
        bf16x8 afrag;
        afrag[0] = f2bf(h0.x); afrag[1] = f2bf(h0.y);
        afrag[2] = f2bf(h0.z); afrag[3] = f2bf(h0.w);
        afrag[4] = f2bf(h1.x); afrag[5] = f2bf(h1.y);
        afrag[6] = f2bf(h1.z); afrag[7] = f2bf(h1.w);
        #pragma unroll
        for (int u = 0; u < 2; ++u) {
            int t = wid * 2 + u;
            bf16x8 bfrag = *reinterpret_cast<const bf16x8*>(
                WTg + (t * 16 + n) * 128 + kc * 32 + q * 8);
            acc[u] = __builtin_amdgcn_mfma_f32_16x16x32_bf16(afrag, bfrag, acc[u], 0, 0, 0);
        }
    }

    float p1[4] = {0.f, 0.f, 0.f, 0.f}, p2[4] = {0.f, 0.f, 0.f, 0.f};
    #pragma unroll
    for (int u = 0; u < 2; ++u) {
        int c = (wid * 2 + u) * 16 + n;
        float a1c = a[c], a2c = a[128 + c];
        #pragma unroll
        for (int r = 0; r < 4; ++r) {
            p1[r] += acc[u][r] * a1c;
            p2[r] += acc[u][r] * a2c;
        }
    }
    #pragma unroll
    for (int d = 1; d < 16; d <<= 1) {
        #pragma unroll
        for (int r = 0; r < 4; ++r) {
            p1[r] += __shfl_xor(p1[r], d);
            p2[r] += __shfl_xor(p2[r], d);
        }
    }
    if (n == 0) {
        #pragma unroll
        for (int r = 0; r < 4; ++r) {
            sred[wid][0][q * 4 + r] = p1[r];
            sred[wid][1][q * 4 + r] = p2[r];
        }
    }

    #pragma unroll
    for (int u = 0; u < 2; ++u)
        #pragma unroll
        for (int r = 0; r < 4; ++r)
            tr[wid][u * 16 + n][q * 4 + r] = f2bf(acc[u][r]);
    __syncthreads();

    if (wid == 0 && lane < 16) {
        float v1 = 0.f, v2 = 0.f;
        #pragma unroll
        for (int v = 0; v < 4; ++v) { v1 += sred[v][0][lane]; v2 += sred[v][1][lane]; }
        s1g[rb + lane] = v1;
        s2g[rb + lane] = v2;
    }

    int jr = rb & 2047;
    int fl = lane & 31, jh = lane >> 5;
    bf16x8 v = *reinterpret_cast<const bf16x8*>(&tr[wid][fl][jh * 8]);
    int f = wid * 32 + fl;
    int t = f >> 4, nn = f & 15;
    int jc = jr >> 5;
    int qg = ((jr & 31) >> 3) + jh;                    // jo>>3 for this 8-run
    *reinterpret_cast<bf16x8*>(
        whT + (size_t)(bb * 64 + jc) * 4096 + t * 512 + qg * 128 + nn * 8) = v;
}

// ---------------------------------------------------------------------------
// Kernel 2 (v12): fused masked-softmax attention + PV.
// 2 waves/SIMD + 2-way B-sharing: grid 512 (8 XCD b x 64 tiles of 32 rows),
// block 256 thr = 4 waves = 2 row-groups (rg) x 2 j-halves (jh). Each jh
// pair co-stages its 8 KB chunks into a double-buffered LDS ring
// (global_load_lds); masks/s2 staged to LDS once. 2 blocks/CU (LDS 48.4 KB,
// VGPR<=256 via __launch_bounds__(256,2)) so barrier drains overlap with the
// other block's waves (v10/v11 ran 1 wave/SIMD — issue-serialized).
// Epilogue: 2-way combine across jh in the ring's LDS.
// ---------------------------------------------------------------------------
__global__ __launch_bounds__(256, 2) void attn_kernel(
        const short* __restrict__ whT, const float* __restrict__ s1g,
        const float* __restrict__ s2g, const uint8_t* __restrict__ adjb,
        float* __restrict__ out) {
    __shared__ char ring[2][2][8192];                  // [jh][slot], 32 KB
    __shared__ uint32_t mlds[32 * 65];                 // 8.32 KB masks
    __shared__ float s2lds[2048];                      // 8 KB s2
    __shared__ float dslds[4][16];                     // per-wave denominators

    int tid = threadIdx.x, wid = tid >> 6, lane = tid & 63;
    int q = lane >> 4, n = lane & 15;
    int rg = wid & 1, jh = wid >> 1;
    int b  = blockIdx.x & 7;                           // XCD-local batch
    int ib = (blockIdx.x >> 3) * 32;                   // i-tile base (0..63)
    int row = ib + rg * 16 + n;                        // this wave's row (m=n)

    float s1A = s1g[b * 2048 + row];
    const char* gbase = reinterpret_cast<const char*>(whT) + (size_t)b * 524288;

    // ---- stage masks: 32 rows x 64 dwords, pitch 65
    {
        int r = tid >> 3, sub = tid & 7;
        const uint4* src = reinterpret_cast<const uint4*>(
            adjb + (size_t)(ib + r) * 256 + sub * 32);
        uint4 v0 = src[0], v1 = src[1];
        uint32_t* dst = &mlds[r * 65 + sub * 8];
        dst[0] = v0.x; dst[1] = v0.y; dst[2] = v0.z; dst[3] = v0.w;
        dst[4] = v1.x; dst[5] = v1.y; dst[6] = v1.z; dst[7] = v1.w;
    }
    // ---- stage s2 (2048 floats)
    {
        const float* s2b = s2g + b * 2048;
        float4 v0 = *reinterpret_cast<const float4*>(s2b + tid * 8);
        float4 v1 = *reinterpret_cast<const float4*>(s2b + tid * 8 + 4);
        *reinterpret_cast<float4*>(&s2lds[tid * 8])     = v0;
        *reinterpret_cast<float4*>(&s2lds[tid * 8 + 4]) = v1;
    }

    // ---- prologue: each jh pair stages its chunk 0 (waves split 4 KB each)
    {
        const char* g = gbase + (size_t)(jh * 32) * 8192 + rg * 4096 + lane * 16;
        char* l = &ring[jh][0][rg * 4096];
        #pragma unroll
        for (int i = 0; i < 4; ++i)
            gload_lds16(g + i * 1024, l + i * 1024);
    }
    __syncthreads();

    f32x4 acc[8] = {};
    float ds = 0.f;
    int mrow = (rg * 16 + n) * 65 + jh * 32;

    for (int c = 0; c < 32; ++c) {
        int cur = c & 1;
        if (c < 31) {                                  // stage chunk c+1
            const char* g = gbase + (size_t)(jh * 32 + c + 1) * 8192
                            + rg * 4096 + lane * 16;
            char* l = &ring[jh][cur ^ 1][rg * 4096];
            #pragma unroll
            for (int i = 0; i < 4; ++i)
                gload_lds16(g + i * 1024, l + i * 1024);
        }

        // ---- B frags from ring (lane*16 contiguous, conflict-free b128)
        const char* cb = &ring[jh][cur][0] + lane * 16;
        bf16x8 nb[8];
        #pragma unroll
        for (int t = 0; t < 8; ++t)
            nb[t] = *reinterpret_cast<const bf16x8*>(cb + t * 1024);

        // ---- mask + s2 from LDS (broadcast-friendly)
        uint32_t mA = mlds[mrow + c] >> (q * 8);
        int sb = (jh * 32 + c) * 32 + q * 8;
        float4 s2a = *reinterpret_cast<const float4*>(&s2lds[sb]);
        float4 s2c = *reinterpret_cast<const float4*>(&s2lds[sb + 4]);
        float s2arr[8] = {s2a.x, s2a.y, s2a.z, s2a.w,
                          s2c.x, s2c.y, s2c.z, s2c.w};

        // ---- P for chunk c
        float p[8];
        #pragma unroll
        for (int j = 0; j < 8; ++j) {
            float e = s1A + s2arr[j];
            e = fmaxf(e, ALPHA * e);
            float v = ((mA >> j) & 1) ? __expf(e) : 0.0f;
            ds += v; p[j] = v;
        }
        union { uint32_t u32[4]; bf16x8 v; } cv;
        #pragma unroll
        for (int pp = 0; pp < 4; ++pp)
            cv.u32[pp] = pk_bf16(p[2 * pp], p[2 * pp + 1]);

        #pragma unroll
        for (int t = 0; t < 8; ++t)
            acc[t] = __builtin_amdgcn_mfma_f32_16x16x32_bf16(cv.v, nb[t], acc[t], 0, 0, 0);

        __syncthreads();                               // slot rotate + stage done
    }

    // ---- intra-wave denominators (row m in lanes m, m+16, m+32, m+48)
    ds += __shfl_xor(ds, 16); ds += __shfl_xor(ds, 32);
    if (q == 0) dslds[wid][n] = ds;

    // ---- 2-way combine across jh (reuse ring as 16 KB buffer)
    f32x4* cbuf = reinterpret_cast<f32x4*>(&ring[0][0][0]);
    __syncthreads();                                   // ring reads done + dslds
    if (jh == 1) {
        #pragma unroll
        for (int i = 0; i < 8; ++i)
            cbuf[(rg * 8 + i) * 64 + lane] = acc[i];
    }
    __syncthreads();
    if (jh == 0) {
        #pragma unroll
        for (int i = 0; i < 8; ++i)
            acc[i] += cbuf[(rg * 8 + i) * 64 + lane];

        float dtot = dslds[rg][n] + dslds[2 + rg][n];
        float rd[4];
        #pragma unroll
        for (int r = 0; r < 4; ++r)
            rd[r] = 1.0f / __shfl(dtot, q * 4 + r);

        size_t ob = ((size_t)b * 2048 + ib + rg * 16) * 128;
        #pragma unroll
        for (int t = 0; t < 8; ++t)
            #pragma unroll
            for (int r = 0; r < 4; ++r)
                out[ob + (size_t)(q * 4 + r) * 128 + t * 16 + n] = acc[t][r] * rd[r];
    }
}

// ---------------------------------------------------------------------------
extern "C" void kernel_launch(void* const* d_in, const int* in_sizes, int n_in,
                              void* d_out, int out_size, void* d_ws, size_t ws_size,
                              hipStream_t stream) {
    const float* h   = (const float*)d_in[0];   // [8][2048][128] f32
    const int*   adj = (const int*)d_in[1];     // [2048][2048] i32
    const float* W   = (const float*)d_in[2];   // [128][128] f32
    const float* a   = (const float*)d_in[3];   // [256][1] f32
    float* out = (float*)d_out;                 // [8][2048][128] f32

    char* ws = (char*)d_ws;
    short* whT = (short*)ws;                                  // 4 MB  bf16 whT (chunk-tiled)
    float* s1  = (float*)(ws + 4194304);                      // 64 KB
    float* s2  = (float*)(ws + 4259840);                      // 64 KB
    uint8_t* bytes = (uint8_t*)(ws + 4325376);                // 512 KB

    // WT scratch in the tail of d_out (32 KB); wh reads it before attn
    // overwrites d_out. Same-stream ordering makes this safe.
    short* WTg = (short*)d_out + (4194304 - 16384);

    pack_adj_kernel<<<2048, 256, 0, stream>>>(adj, bytes, W, WTg);
    wh_kernel<<<1024, 256, 0, stream>>>(h, WTg, a, whT, s1, s2);
    attn_kernel<<<512, 256, 0, stream>>>(whT, s1, s2, bytes, out);
}